// Round 1
// baseline (2923.919 us; speedup 1.0000x reference)
//
#include <hip/hip_runtime.h>
#include <cstdint>
#include <cstddef>

#define NN 50000
#define EE 800000
#define EP (EE + NN)   // 850000 edges incl. appended self-loops
#define DD 128
#define NEG 0.2f
#define EPSL 1e-5f

__device__ inline float wave_reduce_sum(float v) {
    for (int off = 32; off; off >>= 1) v += __shfl_xor(v, off);
    return v;
}
__device__ inline float wave_reduce_max(float v) {
    for (int off = 32; off; off >>= 1) v = fmaxf(v, __shfl_xor(v, off));
    return v;
}

// ---------------- CSR build ----------------

__global__ __launch_bounds__(256) void hist_kernel(const int* __restrict__ ei,
                                                   int* __restrict__ deg) {
    int i = blockIdx.x * 256 + threadIdx.x;
    if (i >= EP) return;
    int dst = (i < EE) ? ei[EE + i] : (i - EE);
    atomicAdd(&deg[dst], 1);
}

// single-block exclusive scan over deg[0..NN) -> row_ptr, cursor
__global__ __launch_bounds__(1024) void scan_kernel(const int* __restrict__ deg,
                                                    int* __restrict__ row_ptr,
                                                    int* __restrict__ cursor) {
    __shared__ int buf[1024];
    __shared__ int carry_s;
    int tid = threadIdx.x;
    if (tid == 0) carry_s = 0;
    __syncthreads();
    for (int base = 0; base < NN; base += 1024) {
        int i = base + tid;
        int v = (i < NN) ? deg[i] : 0;
        buf[tid] = v;
        __syncthreads();
        for (int off = 1; off < 1024; off <<= 1) {
            int t = (tid >= off) ? buf[tid - off] : 0;
            __syncthreads();
            buf[tid] += t;
            __syncthreads();
        }
        int excl = buf[tid] - v;
        int carry = carry_s;
        if (i < NN) { row_ptr[i] = carry + excl; cursor[i] = carry + excl; }
        __syncthreads();
        if (tid == 0) carry_s += buf[1023];
        __syncthreads();
    }
    if (tid == 0) row_ptr[NN] = carry_s;
}

__global__ __launch_bounds__(256) void scatter_kernel(const int* __restrict__ ei,
                                                      int* __restrict__ cursor,
                                                      int* __restrict__ col) {
    int i = blockIdx.x * 256 + threadIdx.x;
    if (i >= EP) return;
    int s, dst; unsigned flag;
    if (i < EE) { s = ei[i]; dst = ei[EE + i]; flag = 0u; }
    else        { s = i - EE; dst = s; flag = 0x80000000u; }  // appended self-loop
    int pos = atomicAdd(&cursor[dst], 1);
    col[pos] = (int)((unsigned)s | flag);
}

// ---------------- GEMM + fused attention dot products ----------------
// H = X @ W   (X: NN x 128, W: 128 x 128 row-major)
// a_src[n,h] = sum_c H[n,h*C+cc]*att_s[h*C+cc]  == per-head partial sums of H[n,c]*att_flat[c]
template <int H>
__global__ __launch_bounds__(128) void gemm_attn(const float* __restrict__ X,
                                                 const float* __restrict__ W,
                                                 const float* __restrict__ att_s,
                                                 const float* __restrict__ att_d,
                                                 float* __restrict__ Hout,
                                                 float* __restrict__ a_src,
                                                 float* __restrict__ a_dst) {
    int tid = threadIdx.x, lane = tid & 63, wave = tid >> 6;
    __shared__ float xs[4][DD];
    __shared__ float ps_s[4][2], ps_d[4][2];
    int row0 = blockIdx.x * 4;
    for (int r = 0; r < 4; ++r) {
        int row = row0 + r;
        xs[r][tid] = (row < NN) ? X[(size_t)row * DD + tid] : 0.f;
    }
    __syncthreads();
    float acc[4] = {0.f, 0.f, 0.f, 0.f};
    for (int k = 0; k < DD; ++k) {
        float w = W[k * DD + tid];
        acc[0] = fmaf(xs[0][k], w, acc[0]);
        acc[1] = fmaf(xs[1][k], w, acc[1]);
        acc[2] = fmaf(xs[2][k], w, acc[2]);
        acc[3] = fmaf(xs[3][k], w, acc[3]);
    }
    float as = att_s[tid], ad = att_d[tid];
    for (int r = 0; r < 4; ++r) {
        int row = row0 + r;
        if (row >= NN) break;
        Hout[(size_t)row * DD + tid] = acc[r];
        float psum = wave_reduce_sum(acc[r] * as);
        float pdum = wave_reduce_sum(acc[r] * ad);
        if (lane == 0) { ps_s[r][wave] = psum; ps_d[r][wave] = pdum; }
    }
    __syncthreads();
    if (tid < 4) {
        int row = row0 + tid;
        if (row < NN) {
            if (H == 2) {
                a_src[row * 2 + 0] = ps_s[tid][0];
                a_src[row * 2 + 1] = ps_s[tid][1];
                a_dst[row * 2 + 0] = ps_d[tid][0];
                a_dst[row * 2 + 1] = ps_d[tid][1];
            } else {
                a_src[row] = ps_s[tid][0] + ps_s[tid][1];
                a_dst[row] = ps_d[tid][0] + ps_d[tid][1];
            }
        }
    }
}

// ---------------- fused GAT softmax + aggregate (+LN stats) ----------------
// one block (128 threads) per destination node; wave == head for H=2
template <int H>
__global__ __launch_bounds__(128) void gat_agg(const int* __restrict__ row_ptr,
                                               const int* __restrict__ col,
                                               const float* __restrict__ Hin,
                                               const float* __restrict__ a_src,
                                               const float* __restrict__ a_dst,
                                               const float* __restrict__ bias,
                                               float* __restrict__ Out,
                                               double* __restrict__ stats) {
    int n = blockIdx.x;
    int tid = threadIdx.x, lane = tid & 63, wave = tid >> 6;
    int beg = row_ptr[n], end = row_ptr[n + 1];
    const int hh = (H == 2) ? wave : 0;
    float ad = a_dst[n * H + hh];

    // pass 1: per-head max over incoming edges (wave-strided)
    float m = -1e30f;
    for (int pos = beg + lane; pos < end; pos += 64) {
        int s = col[pos] & 0x7fffffff;
        float e = a_src[s * H + hh] + ad;
        e = (e > 0.f) ? e : NEG * e;
        m = fmaxf(m, e);
    }
    m = wave_reduce_max(m);

    // pass 2: accumulate weighted features + denominator
    float accv = 0.f, den = 0.f;
    for (int pos = beg; pos < end; ++pos) {
        int s = col[pos] & 0x7fffffff;
        float e = a_src[s * H + hh] + ad;
        e = (e > 0.f) ? e : NEG * e;
        float w = __expf(e - m);
        den += w;
        accv = fmaf(w, Hin[(size_t)s * DD + tid], accv);
    }
    float out = accv / (den + 1e-16f) + bias[tid];
    Out[(size_t)n * DD + tid] = out;

    // LN (graph mode) partial stats
    float s1 = wave_reduce_sum(out);
    float s2 = wave_reduce_sum(out * out);
    __shared__ float red[4];
    if (lane == 0) { red[wave] = s1; red[2 + wave] = s2; }
    __syncthreads();
    if (tid == 0) {
        atomicAdd(&stats[0], (double)(red[0] + red[1]));
        atomicAdd(&stats[1], (double)(red[2] + red[3]));
    }
}

// ---------------- graph LayerNorm apply (optionally + relu), in place ----------------
__global__ __launch_bounds__(256) void ln_kernel(float* __restrict__ buf,
                                                 const double* __restrict__ stats,
                                                 const float* __restrict__ w,
                                                 const float* __restrict__ b,
                                                 int do_relu) {
    int i = blockIdx.x * 256 + threadIdx.x;
    if (i >= NN * DD) return;
    int c = i & (DD - 1);
    const double M = (double)NN * DD;
    double mean_d = stats[0] / M;
    double var_d = stats[1] / M - mean_d * mean_d;
    float mean = (float)mean_d;
    float inv = rsqrtf((float)var_d + EPSL);
    float v = buf[i];
    float val = (v - mean) * inv * w[c] + b[c];
    if (do_relu) val = fmaxf(val, 0.f);
    buf[i] = val;
}

// ---------------- SimpleConv(mean over ORIGINAL edges) + residual + relu ----------------
__global__ __launch_bounds__(128) void simpleconv_kernel(const int* __restrict__ row_ptr,
                                                         const int* __restrict__ col,
                                                         const float* __restrict__ Hin,
                                                         const float* __restrict__ X,
                                                         float* __restrict__ Out) {
    int n = blockIdx.x, tid = threadIdx.x;
    int beg = row_ptr[n], end = row_ptr[n + 1];
    float acc = 0.f;
    int cnt = 0;
    for (int pos = beg; pos < end; ++pos) {
        int cv = col[pos];
        if (cv >= 0) {  // skip appended self-loops (top bit set)
            acc += Hin[(size_t)cv * DD + tid];
            cnt++;
        }
    }
    float mean = acc / (float)((cnt > 0) ? cnt : 1);
    float val = mean + X[(size_t)n * DD + tid];
    Out[(size_t)n * DD + tid] = fmaxf(val, 0.f);
}

extern "C" void kernel_launch(void* const* d_in, const int* in_sizes, int n_in,
                              void* d_out, int out_size, void* d_ws, size_t ws_size,
                              hipStream_t stream) {
    const float* x    = (const float*)d_in[0];
    const int*   ei   = (const int*)d_in[1];
    const float* W1   = (const float*)d_in[2];
    const float* as1  = (const float*)d_in[3];
    const float* ad1  = (const float*)d_in[4];
    const float* b1   = (const float*)d_in[5];
    const float* ln1w = (const float*)d_in[6];
    const float* ln1b = (const float*)d_in[7];
    const float* W2   = (const float*)d_in[8];
    const float* as2  = (const float*)d_in[9];
    const float* ad2  = (const float*)d_in[10];
    const float* b2   = (const float*)d_in[11];
    const float* ln2w = (const float*)d_in[12];
    const float* ln2b = (const float*)d_in[13];
    float* out = (float*)d_out;

    char* p = (char*)d_ws;
    auto alloc = [&](size_t bytes) {
        void* r = (void*)p;
        p += (bytes + 255) & ~(size_t)255;
        return r;
    };
    int*    deg     = (int*)alloc((size_t)NN * 4);
    int*    row_ptr = (int*)alloc((size_t)(NN + 1) * 4);
    int*    cursor  = (int*)alloc((size_t)NN * 4);
    double* stats1  = (double*)alloc(16);
    double* stats2  = (double*)alloc(16);
    int*    col     = (int*)alloc((size_t)EP * 4);
    float*  bufA    = (float*)alloc((size_t)NN * DD * 4);  // h1, later h2
    float*  bufB    = (float*)alloc((size_t)NN * DD * 4);  // out1/hln1, later out2/hln2
    float*  aS1     = (float*)alloc((size_t)NN * 2 * 4);
    float*  aD1     = (float*)alloc((size_t)NN * 2 * 4);
    float*  aS2     = (float*)alloc((size_t)NN * 4);
    float*  aD2     = (float*)alloc((size_t)NN * 4);

    hipMemsetAsync(deg, 0, (size_t)NN * 4, stream);
    hipMemsetAsync(stats1, 0, 16, stream);
    hipMemsetAsync(stats2, 0, 16, stream);

    hist_kernel<<<(EP + 255) / 256, 256, 0, stream>>>(ei, deg);
    scan_kernel<<<1, 1024, 0, stream>>>(deg, row_ptr, cursor);
    scatter_kernel<<<(EP + 255) / 256, 256, 0, stream>>>(ei, cursor, col);

    // layer 1: GATConv(128 -> 64, heads=2, concat) + graph-LN + relu
    gemm_attn<2><<<(NN + 3) / 4, 128, 0, stream>>>(x, W1, as1, ad1, bufA, aS1, aD1);
    gat_agg<2><<<NN, 128, 0, stream>>>(row_ptr, col, bufA, aS1, aD1, b1, bufB, stats1);
    ln_kernel<<<(NN * DD + 255) / 256, 256, 0, stream>>>(bufB, stats1, ln1w, ln1b, 1);

    // layer 2: GATConv(128 -> 128, heads=1) + graph-LN
    gemm_attn<1><<<(NN + 3) / 4, 128, 0, stream>>>(bufB, W2, as2, ad2, bufA, aS2, aD2);
    gat_agg<1><<<NN, 128, 0, stream>>>(row_ptr, col, bufA, aS2, aD2, b2, bufB, stats2);
    ln_kernel<<<(NN * DD + 255) / 256, 256, 0, stream>>>(bufB, stats2, ln2w, ln2b, 0);

    // SimpleConv mean over original edges + residual + relu
    simpleconv_kernel<<<NN, 128, 0, stream>>>(row_ptr, col, bufB, x, out);
}

// Round 2
// 2840.144 us; speedup vs baseline: 1.0295x; 1.0295x over previous
//
#include <hip/hip_runtime.h>
#include <cstdint>
#include <cstddef>

#define NN 50000
#define EE 800000
#define EP (EE + NN)   // 850000 edges incl. appended self-loops
#define DD 128
#define NEG 0.2f
#define EPSL 1e-5f
#define CHUNK 512

__device__ inline float wave_reduce_sum(float v) {
    for (int off = 32; off; off >>= 1) v += __shfl_xor(v, off);
    return v;
}
__device__ inline float wave_reduce_max(float v) {
    for (int off = 32; off; off >>= 1) v = fmaxf(v, __shfl_xor(v, off));
    return v;
}

// ---------------- CSR build ----------------

__global__ __launch_bounds__(256) void hist_kernel(const int* __restrict__ ei,
                                                   int* __restrict__ deg) {
    int i = blockIdx.x * 256 + threadIdx.x;
    if (i >= EP) return;
    int dst = (i < EE) ? ei[EE + i] : (i - EE);
    atomicAdd(&deg[dst], 1);
}

// single-block exclusive scan over deg[0..NN) -> row_ptr, cursor (shuffle-based)
__global__ __launch_bounds__(1024) void scan_kernel(const int* __restrict__ deg,
                                                    int* __restrict__ row_ptr,
                                                    int* __restrict__ cursor) {
    __shared__ int wsum[16];
    __shared__ int carry_s;
    int tid = threadIdx.x, lane = tid & 63, wv = tid >> 6;  // 16 waves
    if (tid == 0) carry_s = 0;
    __syncthreads();
    for (int base = 0; base < NN; base += 1024) {
        int i = base + tid;
        int v = (i < NN) ? deg[i] : 0;
        // inclusive wave scan
        int x = v;
        for (int off = 1; off < 64; off <<= 1) {
            int t = __shfl_up(x, off);
            if (lane >= off) x += t;
        }
        if (lane == 63) wsum[wv] = x;
        __syncthreads();
        if (wv == 0) {
            int s = (lane < 16) ? wsum[lane] : 0;
            for (int off = 1; off < 16; off <<= 1) {
                int t = __shfl_up(s, off);
                if (lane >= off) s += t;
            }
            if (lane < 16) wsum[lane] = s;  // inclusive scan of wave sums
        }
        __syncthreads();
        int waveoff = (wv == 0) ? 0 : wsum[wv - 1];
        int excl = x + waveoff - v;
        int carry = carry_s;
        if (i < NN) { row_ptr[i] = carry + excl; cursor[i] = carry + excl; }
        __syncthreads();
        if (tid == 0) carry_s += wsum[15];
        __syncthreads();
    }
    if (tid == 0) row_ptr[NN] = carry_s;
}

__global__ __launch_bounds__(256) void scatter_kernel(const int* __restrict__ ei,
                                                      int* __restrict__ cursor,
                                                      int* __restrict__ col) {
    int i = blockIdx.x * 256 + threadIdx.x;
    if (i >= EP) return;
    int s, dst; unsigned flag;
    if (i < EE) { s = ei[i]; dst = ei[EE + i]; flag = 0u; }
    else        { s = i - EE; dst = s; flag = 0x80000000u; }  // appended self-loop
    int pos = atomicAdd(&cursor[dst], 1);
    col[pos] = (int)((unsigned)s | flag);
}

// ---------------- GEMM + fused attention dot products ----------------
template <int H>
__global__ __launch_bounds__(128) void gemm_attn(const float* __restrict__ X,
                                                 const float* __restrict__ W,
                                                 const float* __restrict__ att_s,
                                                 const float* __restrict__ att_d,
                                                 float* __restrict__ Hout,
                                                 float* __restrict__ a_src,
                                                 float* __restrict__ a_dst) {
    int tid = threadIdx.x, lane = tid & 63, wave = tid >> 6;
    __shared__ float xs[4][DD];
    __shared__ float ps_s[4][2], ps_d[4][2];
    int row0 = blockIdx.x * 4;
    for (int r = 0; r < 4; ++r) {
        int row = row0 + r;
        xs[r][tid] = (row < NN) ? X[(size_t)row * DD + tid] : 0.f;
    }
    __syncthreads();
    float acc[4] = {0.f, 0.f, 0.f, 0.f};
    for (int k = 0; k < DD; ++k) {
        float w = W[k * DD + tid];
        acc[0] = fmaf(xs[0][k], w, acc[0]);
        acc[1] = fmaf(xs[1][k], w, acc[1]);
        acc[2] = fmaf(xs[2][k], w, acc[2]);
        acc[3] = fmaf(xs[3][k], w, acc[3]);
    }
    float as = att_s[tid], ad = att_d[tid];
    for (int r = 0; r < 4; ++r) {
        int row = row0 + r;
        if (row >= NN) break;
        Hout[(size_t)row * DD + tid] = acc[r];
        float psum = wave_reduce_sum(acc[r] * as);
        float pdum = wave_reduce_sum(acc[r] * ad);
        if (lane == 0) { ps_s[r][wave] = psum; ps_d[r][wave] = pdum; }
    }
    __syncthreads();
    if (tid < 4) {
        int row = row0 + tid;
        if (row < NN) {
            if (H == 2) {
                a_src[row * 2 + 0] = ps_s[tid][0];
                a_src[row * 2 + 1] = ps_s[tid][1];
                a_dst[row * 2 + 0] = ps_d[tid][0];
                a_dst[row * 2 + 1] = ps_d[tid][1];
            } else {
                a_src[row] = ps_s[tid][0] + ps_s[tid][1];
                a_dst[row] = ps_d[tid][0] + ps_d[tid][1];
            }
        }
    }
}

// ---------------- fused GAT softmax + aggregate (+LN stats) ----------------
// one block (128 threads) per destination node; wave == head for H=2
template <int H>
__global__ __launch_bounds__(128) void gat_agg(const int* __restrict__ row_ptr,
                                               const int* __restrict__ col,
                                               const float* __restrict__ Hin,
                                               const float* __restrict__ a_src,
                                               const float* __restrict__ a_dst,
                                               const float* __restrict__ bias,
                                               float* __restrict__ Out,
                                               double* __restrict__ stats) {
    int n = blockIdx.x;
    int tid = threadIdx.x, lane = tid & 63, wave = tid >> 6;
    int beg = row_ptr[n], end = row_ptr[n + 1];
    int deg = end - beg;

    __shared__ int   s_src[CHUNK];
    __shared__ float s_w[H][CHUNK];
    __shared__ float s_red[8];

    float ad0 = a_dst[n * H + 0];
    float ad1 = (H == 2) ? a_dst[n * H + 1] : 0.f;

    // ---- phase 1: global max per head (parallel gathers, no staging) ----
    float m0 = -1e30f, m1 = -1e30f;
    for (int i = tid; i < deg; i += 128) {
        int s = col[beg + i] & 0x7fffffff;
        if (H == 2) {
            float2 av = *(const float2*)&a_src[s * 2];
            float e0 = av.x + ad0; e0 = (e0 > 0.f) ? e0 : NEG * e0;
            float e1 = av.y + ad1; e1 = (e1 > 0.f) ? e1 : NEG * e1;
            m0 = fmaxf(m0, e0); m1 = fmaxf(m1, e1);
        } else {
            float e0 = a_src[s] + ad0; e0 = (e0 > 0.f) ? e0 : NEG * e0;
            m0 = fmaxf(m0, e0);
        }
    }
    m0 = wave_reduce_max(m0);
    if (H == 2) m1 = wave_reduce_max(m1);
    if (lane == 0) { s_red[wave] = m0; if (H == 2) s_red[2 + wave] = m1; }
    __syncthreads();
    m0 = fmaxf(s_red[0], s_red[1]);
    if (H == 2) m1 = fmaxf(s_red[2], s_red[3]);

    // ---- phase 2: chunked stage (col + exp weights into LDS) + accumulate ----
    float accv = 0.f;
    float dloc0 = 0.f, dloc1 = 0.f;
    for (int c0 = 0; c0 < deg; c0 += CHUNK) {
        int cn = min(CHUNK, deg - c0);
        __syncthreads();  // protect LDS reuse across chunks / after max reduce
        for (int i = tid; i < cn; i += 128) {
            int s = col[beg + c0 + i] & 0x7fffffff;
            s_src[i] = s;
            if (H == 2) {
                float2 av = *(const float2*)&a_src[s * 2];
                float e0 = av.x + ad0; e0 = (e0 > 0.f) ? e0 : NEG * e0;
                float e1 = av.y + ad1; e1 = (e1 > 0.f) ? e1 : NEG * e1;
                float w0 = __expf(e0 - m0), w1 = __expf(e1 - m1);
                s_w[0][i] = w0; s_w[1][i] = w1;
                dloc0 += w0; dloc1 += w1;
            } else {
                float e0 = a_src[s] + ad0; e0 = (e0 > 0.f) ? e0 : NEG * e0;
                float w0 = __expf(e0 - m0);
                s_w[0][i] = w0;
                dloc0 += w0;
            }
        }
        __syncthreads();
        const float* wrow = (H == 2) ? s_w[wave] : s_w[0];
        int i = 0;
        for (; i + 8 <= cn; i += 8) {
            int ss[8]; float ww[8], hv[8];
            #pragma unroll
            for (int u = 0; u < 8; ++u) { ss[u] = s_src[i + u]; ww[u] = wrow[i + u]; }
            #pragma unroll
            for (int u = 0; u < 8; ++u) { hv[u] = Hin[(size_t)ss[u] * DD + tid]; }
            #pragma unroll
            for (int u = 0; u < 8; ++u) { accv = fmaf(ww[u], hv[u], accv); }
        }
        for (; i < cn; ++i) accv = fmaf(wrow[i], Hin[(size_t)s_src[i] * DD + tid], accv);
    }

    // ---- reduce denominator across block ----
    float d0 = wave_reduce_sum(dloc0);
    float d1 = (H == 2) ? wave_reduce_sum(dloc1) : 0.f;
    __syncthreads();
    if (lane == 0) { s_red[wave] = d0; if (H == 2) s_red[2 + wave] = d1; }
    __syncthreads();
    float den;
    if (H == 2) den = (wave == 0) ? (s_red[0] + s_red[1]) : (s_red[2] + s_red[3]);
    else        den = s_red[0] + s_red[1];

    float out = accv / (den + 1e-16f) + bias[tid];
    Out[(size_t)n * DD + tid] = out;

    // LN (graph mode) partial stats
    float s1 = wave_reduce_sum(out);
    float s2 = wave_reduce_sum(out * out);
    __shared__ float red2[4];
    if (lane == 0) { red2[wave] = s1; red2[2 + wave] = s2; }
    __syncthreads();
    if (tid == 0) {
        atomicAdd(&stats[0], (double)(red2[0] + red2[1]));
        atomicAdd(&stats[1], (double)(red2[2] + red2[3]));
    }
}

// ---------------- graph LayerNorm apply (optionally + relu), in place ----------------
__global__ __launch_bounds__(256) void ln_kernel(float* __restrict__ buf,
                                                 const double* __restrict__ stats,
                                                 const float* __restrict__ w,
                                                 const float* __restrict__ b,
                                                 int do_relu) {
    int i = blockIdx.x * 256 + threadIdx.x;
    if (i >= NN * DD) return;
    int c = i & (DD - 1);
    const double M = (double)NN * DD;
    double mean_d = stats[0] / M;
    double var_d = stats[1] / M - mean_d * mean_d;
    float mean = (float)mean_d;
    float inv = rsqrtf((float)var_d + EPSL);
    float v = buf[i];
    float val = (v - mean) * inv * w[c] + b[c];
    if (do_relu) val = fmaxf(val, 0.f);
    buf[i] = val;
}

// ---------------- SimpleConv(mean over ORIGINAL edges) + residual + relu ----------------
// sum over ALL csr edges (incl. the one appended self-loop) minus Hin[n]; cnt = deg-1
__global__ __launch_bounds__(128) void simpleconv_kernel(const int* __restrict__ row_ptr,
                                                         const int* __restrict__ col,
                                                         const float* __restrict__ Hin,
                                                         const float* __restrict__ X,
                                                         float* __restrict__ Out) {
    int n = blockIdx.x, tid = threadIdx.x;
    int beg = row_ptr[n], end = row_ptr[n + 1];
    int deg = end - beg;
    __shared__ int s_src[CHUNK];
    float acc = 0.f;
    for (int c0 = 0; c0 < deg; c0 += CHUNK) {
        int cn = min(CHUNK, deg - c0);
        __syncthreads();
        for (int i = tid; i < cn; i += 128)
            s_src[i] = col[beg + c0 + i] & 0x7fffffff;
        __syncthreads();
        int i = 0;
        for (; i + 8 <= cn; i += 8) {
            int ss[8]; float hv[8];
            #pragma unroll
            for (int u = 0; u < 8; ++u) ss[u] = s_src[i + u];
            #pragma unroll
            for (int u = 0; u < 8; ++u) hv[u] = Hin[(size_t)ss[u] * DD + tid];
            #pragma unroll
            for (int u = 0; u < 8; ++u) acc += hv[u];
        }
        for (; i < cn; ++i) acc += Hin[(size_t)s_src[i] * DD + tid];
    }
    acc -= Hin[(size_t)n * DD + tid];          // remove appended self-loop
    int cnt = deg - 1;
    float mean = acc / (float)((cnt > 0) ? cnt : 1);
    float val = mean + X[(size_t)n * DD + tid];
    Out[(size_t)n * DD + tid] = fmaxf(val, 0.f);
}

extern "C" void kernel_launch(void* const* d_in, const int* in_sizes, int n_in,
                              void* d_out, int out_size, void* d_ws, size_t ws_size,
                              hipStream_t stream) {
    const float* x    = (const float*)d_in[0];
    const int*   ei   = (const int*)d_in[1];
    const float* W1   = (const float*)d_in[2];
    const float* as1  = (const float*)d_in[3];
    const float* ad1  = (const float*)d_in[4];
    const float* b1   = (const float*)d_in[5];
    const float* ln1w = (const float*)d_in[6];
    const float* ln1b = (const float*)d_in[7];
    const float* W2   = (const float*)d_in[8];
    const float* as2  = (const float*)d_in[9];
    const float* ad2  = (const float*)d_in[10];
    const float* b2   = (const float*)d_in[11];
    const float* ln2w = (const float*)d_in[12];
    const float* ln2b = (const float*)d_in[13];
    float* out = (float*)d_out;

    char* p = (char*)d_ws;
    auto alloc = [&](size_t bytes) {
        void* r = (void*)p;
        p += (bytes + 255) & ~(size_t)255;
        return r;
    };
    int*    deg     = (int*)alloc((size_t)NN * 4);
    int*    row_ptr = (int*)alloc((size_t)(NN + 1) * 4);
    int*    cursor  = (int*)alloc((size_t)NN * 4);
    double* stats1  = (double*)alloc(16);
    double* stats2  = (double*)alloc(16);
    int*    col     = (int*)alloc((size_t)EP * 4);
    float*  bufA    = (float*)alloc((size_t)NN * DD * 4);  // h1, later h2
    float*  bufB    = (float*)alloc((size_t)NN * DD * 4);  // out1/hln1, later out2/hln2
    float*  aS1     = (float*)alloc((size_t)NN * 2 * 4);
    float*  aD1     = (float*)alloc((size_t)NN * 2 * 4);
    float*  aS2     = (float*)alloc((size_t)NN * 4);
    float*  aD2     = (float*)alloc((size_t)NN * 4);

    hipMemsetAsync(deg, 0, (size_t)NN * 4, stream);
    hipMemsetAsync(stats1, 0, 16, stream);
    hipMemsetAsync(stats2, 0, 16, stream);

    hist_kernel<<<(EP + 255) / 256, 256, 0, stream>>>(ei, deg);
    scan_kernel<<<1, 1024, 0, stream>>>(deg, row_ptr, cursor);
    scatter_kernel<<<(EP + 255) / 256, 256, 0, stream>>>(ei, cursor, col);

    // layer 1: GATConv(128 -> 64, heads=2, concat) + graph-LN + relu
    gemm_attn<2><<<(NN + 3) / 4, 128, 0, stream>>>(x, W1, as1, ad1, bufA, aS1, aD1);
    gat_agg<2><<<NN, 128, 0, stream>>>(row_ptr, col, bufA, aS1, aD1, b1, bufB, stats1);
    ln_kernel<<<(NN * DD + 255) / 256, 256, 0, stream>>>(bufB, stats1, ln1w, ln1b, 1);

    // layer 2: GATConv(128 -> 128, heads=1) + graph-LN
    gemm_attn<1><<<(NN + 3) / 4, 128, 0, stream>>>(bufB, W2, as2, ad2, bufA, aS2, aD2);
    gat_agg<1><<<NN, 128, 0, stream>>>(row_ptr, col, bufA, aS2, aD2, b2, bufB, stats2);
    ln_kernel<<<(NN * DD + 255) / 256, 256, 0, stream>>>(bufB, stats2, ln2w, ln2b, 0);

    // SimpleConv mean over original edges + residual + relu
    simpleconv_kernel<<<NN, 128, 0, stream>>>(row_ptr, col, bufB, x, out);
}

// Round 3
// 597.159 us; speedup vs baseline: 4.8964x; 4.7561x over previous
//
#include <hip/hip_runtime.h>
#include <cstdint>
#include <cstddef>

#define NN 50000
#define EE 800000
#define EP (EE + NN)   // 850000 edges incl. appended self-loops
#define DD 128
#define NEG 0.2f
#define EPSL 1e-5f
#define CHUNK 512

__device__ inline float wave_reduce_sum(float v) {
    for (int off = 32; off; off >>= 1) v += __shfl_xor(v, off);
    return v;
}
__device__ inline float wave_reduce_max(float v) {
    for (int off = 32; off; off >>= 1) v = fmaxf(v, __shfl_xor(v, off));
    return v;
}

// ---------------- CSR build ----------------

__global__ __launch_bounds__(256) void hist_kernel(const int* __restrict__ ei,
                                                   int* __restrict__ deg) {
    int i = blockIdx.x * 256 + threadIdx.x;
    if (i >= EP) return;
    int dst = (i < EE) ? ei[EE + i] : (i - EE);
    atomicAdd(&deg[dst], 1);
}

// single-block exclusive scan over deg[0..NN) -> row_ptr, cursor (shuffle-based)
__global__ __launch_bounds__(1024) void scan_kernel(const int* __restrict__ deg,
                                                    int* __restrict__ row_ptr,
                                                    int* __restrict__ cursor) {
    __shared__ int wsum[16];
    __shared__ int carry_s;
    int tid = threadIdx.x, lane = tid & 63, wv = tid >> 6;  // 16 waves
    if (tid == 0) carry_s = 0;
    __syncthreads();
    for (int base = 0; base < NN; base += 1024) {
        int i = base + tid;
        int v = (i < NN) ? deg[i] : 0;
        int x = v;
        for (int off = 1; off < 64; off <<= 1) {
            int t = __shfl_up(x, off);
            if (lane >= off) x += t;
        }
        if (lane == 63) wsum[wv] = x;
        __syncthreads();
        if (wv == 0) {
            int s = (lane < 16) ? wsum[lane] : 0;
            for (int off = 1; off < 16; off <<= 1) {
                int t = __shfl_up(s, off);
                if (lane >= off) s += t;
            }
            if (lane < 16) wsum[lane] = s;
        }
        __syncthreads();
        int waveoff = (wv == 0) ? 0 : wsum[wv - 1];
        int excl = x + waveoff - v;
        int carry = carry_s;
        if (i < NN) { row_ptr[i] = carry + excl; cursor[i] = carry + excl; }
        __syncthreads();
        if (tid == 0) carry_s += wsum[15];
        __syncthreads();
    }
    if (tid == 0) row_ptr[NN] = carry_s;
}

__global__ __launch_bounds__(256) void scatter_kernel(const int* __restrict__ ei,
                                                      int* __restrict__ cursor,
                                                      int* __restrict__ col) {
    int i = blockIdx.x * 256 + threadIdx.x;
    if (i >= EP) return;
    int s, dst; unsigned flag;
    if (i < EE) { s = ei[i]; dst = ei[EE + i]; flag = 0u; }
    else        { s = i - EE; dst = s; flag = 0x80000000u; }  // appended self-loop
    int pos = atomicAdd(&cursor[dst], 1);
    col[pos] = (int)((unsigned)s | flag);
}

// ---------------- GEMM + fused attention dot products ----------------
template <int H>
__global__ __launch_bounds__(128) void gemm_attn(const float* __restrict__ X,
                                                 const float* __restrict__ W,
                                                 const float* __restrict__ att_s,
                                                 const float* __restrict__ att_d,
                                                 float* __restrict__ Hout,
                                                 float* __restrict__ a_src,
                                                 float* __restrict__ a_dst) {
    int tid = threadIdx.x, lane = tid & 63, wave = tid >> 6;
    __shared__ float xs[4][DD];
    __shared__ float ps_s[4][2], ps_d[4][2];
    int row0 = blockIdx.x * 4;
    for (int r = 0; r < 4; ++r) {
        int row = row0 + r;
        xs[r][tid] = (row < NN) ? X[(size_t)row * DD + tid] : 0.f;
    }
    __syncthreads();
    float acc[4] = {0.f, 0.f, 0.f, 0.f};
    for (int k = 0; k < DD; ++k) {
        float w = W[k * DD + tid];
        acc[0] = fmaf(xs[0][k], w, acc[0]);
        acc[1] = fmaf(xs[1][k], w, acc[1]);
        acc[2] = fmaf(xs[2][k], w, acc[2]);
        acc[3] = fmaf(xs[3][k], w, acc[3]);
    }
    float as = att_s[tid], ad = att_d[tid];
    for (int r = 0; r < 4; ++r) {
        int row = row0 + r;
        if (row >= NN) break;
        Hout[(size_t)row * DD + tid] = acc[r];
        float psum = wave_reduce_sum(acc[r] * as);
        float pdum = wave_reduce_sum(acc[r] * ad);
        if (lane == 0) { ps_s[r][wave] = psum; ps_d[r][wave] = pdum; }
    }
    __syncthreads();
    if (tid < 4) {
        int row = row0 + tid;
        if (row < NN) {
            if (H == 2) {
                a_src[row * 2 + 0] = ps_s[tid][0];
                a_src[row * 2 + 1] = ps_s[tid][1];
                a_dst[row * 2 + 0] = ps_d[tid][0];
                a_dst[row * 2 + 1] = ps_d[tid][1];
            } else {
                a_src[row] = ps_s[tid][0] + ps_s[tid][1];
                a_dst[row] = ps_d[tid][0] + ps_d[tid][1];
            }
        }
    }
}

// ---------------- fused GAT softmax + aggregate (+per-block LN partials) ----------------
// one block (128 threads) per destination node; wave == head for H=2
template <int H>
__global__ __launch_bounds__(128) void gat_agg(const int* __restrict__ row_ptr,
                                               const int* __restrict__ col,
                                               const float* __restrict__ Hin,
                                               const float* __restrict__ a_src,
                                               const float* __restrict__ a_dst,
                                               const float* __restrict__ bias,
                                               float* __restrict__ Out,
                                               float2* __restrict__ pstats) {
    int n = blockIdx.x;
    int tid = threadIdx.x, lane = tid & 63, wave = tid >> 6;
    int beg = row_ptr[n], end = row_ptr[n + 1];
    int deg = end - beg;

    __shared__ int   s_src[CHUNK];
    __shared__ float s_w[H][CHUNK];
    __shared__ float s_red[8];

    float ad0 = a_dst[n * H + 0];
    float ad1 = (H == 2) ? a_dst[n * H + 1] : 0.f;

    // ---- phase 1: global max per head (parallel gathers) ----
    float m0 = -1e30f, m1 = -1e30f;
    for (int i = tid; i < deg; i += 128) {
        int s = col[beg + i] & 0x7fffffff;
        if (H == 2) {
            float2 av = *(const float2*)&a_src[s * 2];
            float e0 = av.x + ad0; e0 = (e0 > 0.f) ? e0 : NEG * e0;
            float e1 = av.y + ad1; e1 = (e1 > 0.f) ? e1 : NEG * e1;
            m0 = fmaxf(m0, e0); m1 = fmaxf(m1, e1);
        } else {
            float e0 = a_src[s] + ad0; e0 = (e0 > 0.f) ? e0 : NEG * e0;
            m0 = fmaxf(m0, e0);
        }
    }
    m0 = wave_reduce_max(m0);
    if (H == 2) m1 = wave_reduce_max(m1);
    if (lane == 0) { s_red[wave] = m0; if (H == 2) s_red[2 + wave] = m1; }
    __syncthreads();
    m0 = fmaxf(s_red[0], s_red[1]);
    if (H == 2) m1 = fmaxf(s_red[2], s_red[3]);

    // ---- phase 2: chunked stage (col + exp weights into LDS) + accumulate ----
    float accv = 0.f;
    float dloc0 = 0.f, dloc1 = 0.f;
    for (int c0 = 0; c0 < deg; c0 += CHUNK) {
        int cn = min(CHUNK, deg - c0);
        __syncthreads();
        for (int i = tid; i < cn; i += 128) {
            int s = col[beg + c0 + i] & 0x7fffffff;
            s_src[i] = s;
            if (H == 2) {
                float2 av = *(const float2*)&a_src[s * 2];
                float e0 = av.x + ad0; e0 = (e0 > 0.f) ? e0 : NEG * e0;
                float e1 = av.y + ad1; e1 = (e1 > 0.f) ? e1 : NEG * e1;
                float w0 = __expf(e0 - m0), w1 = __expf(e1 - m1);
                s_w[0][i] = w0; s_w[1][i] = w1;
                dloc0 += w0; dloc1 += w1;
            } else {
                float e0 = a_src[s] + ad0; e0 = (e0 > 0.f) ? e0 : NEG * e0;
                float w0 = __expf(e0 - m0);
                s_w[0][i] = w0;
                dloc0 += w0;
            }
        }
        __syncthreads();
        const float* wrow = (H == 2) ? s_w[wave] : s_w[0];
        int i = 0;
        for (; i + 8 <= cn; i += 8) {
            int ss[8]; float ww[8], hv[8];
            #pragma unroll
            for (int u = 0; u < 8; ++u) { ss[u] = s_src[i + u]; ww[u] = wrow[i + u]; }
            #pragma unroll
            for (int u = 0; u < 8; ++u) { hv[u] = Hin[(size_t)ss[u] * DD + tid]; }
            #pragma unroll
            for (int u = 0; u < 8; ++u) { accv = fmaf(ww[u], hv[u], accv); }
        }
        for (; i < cn; ++i) accv = fmaf(wrow[i], Hin[(size_t)s_src[i] * DD + tid], accv);
    }

    // ---- reduce denominator across block ----
    float d0 = wave_reduce_sum(dloc0);
    float d1 = (H == 2) ? wave_reduce_sum(dloc1) : 0.f;
    __syncthreads();
    if (lane == 0) { s_red[wave] = d0; if (H == 2) s_red[2 + wave] = d1; }
    __syncthreads();
    float den;
    if (H == 2) den = (wave == 0) ? (s_red[0] + s_red[1]) : (s_red[2] + s_red[3]);
    else        den = s_red[0] + s_red[1];

    float out = accv / (den + 1e-16f) + bias[tid];
    Out[(size_t)n * DD + tid] = out;

    // LN (graph mode) partial stats -> per-block store (NO same-address atomics)
    float s1 = wave_reduce_sum(out);
    float s2 = wave_reduce_sum(out * out);
    __shared__ float red2[4];
    if (lane == 0) { red2[wave] = s1; red2[2 + wave] = s2; }
    __syncthreads();
    if (tid == 0) {
        pstats[n] = make_float2(red2[0] + red2[1], red2[2] + red2[3]);
    }
}

// ---------------- deterministic single-block reduce of per-node LN partials ----------------
__global__ __launch_bounds__(1024) void reduce_stats_kernel(const float2* __restrict__ pstats,
                                                            double* __restrict__ stats) {
    int tid = threadIdx.x, lane = tid & 63, wv = tid >> 6;
    double s1 = 0.0, s2 = 0.0;
    for (int i = tid; i < NN; i += 1024) {
        float2 v = pstats[i];
        s1 += (double)v.x; s2 += (double)v.y;
    }
    for (int off = 32; off; off >>= 1) {
        s1 += __shfl_xor(s1, off);
        s2 += __shfl_xor(s2, off);
    }
    __shared__ double w1[16], w2[16];
    if (lane == 0) { w1[wv] = s1; w2[wv] = s2; }
    __syncthreads();
    if (tid == 0) {
        double a = 0.0, b = 0.0;
        for (int i = 0; i < 16; ++i) { a += w1[i]; b += w2[i]; }
        stats[0] = a; stats[1] = b;
    }
}

// ---------------- graph LayerNorm apply (optionally + relu), in place ----------------
__global__ __launch_bounds__(256) void ln_kernel(float* __restrict__ buf,
                                                 const double* __restrict__ stats,
                                                 const float* __restrict__ w,
                                                 const float* __restrict__ b,
                                                 int do_relu) {
    int i = blockIdx.x * 256 + threadIdx.x;
    if (i >= NN * DD) return;
    int c = i & (DD - 1);
    const double M = (double)NN * DD;
    double mean_d = stats[0] / M;
    double var_d = stats[1] / M - mean_d * mean_d;
    float mean = (float)mean_d;
    float inv = rsqrtf((float)var_d + EPSL);
    float v = buf[i];
    float val = (v - mean) * inv * w[c] + b[c];
    if (do_relu) val = fmaxf(val, 0.f);
    buf[i] = val;
}

// ---------------- SimpleConv(mean over ORIGINAL edges) + residual + relu ----------------
__global__ __launch_bounds__(128) void simpleconv_kernel(const int* __restrict__ row_ptr,
                                                         const int* __restrict__ col,
                                                         const float* __restrict__ Hin,
                                                         const float* __restrict__ X,
                                                         float* __restrict__ Out) {
    int n = blockIdx.x, tid = threadIdx.x;
    int beg = row_ptr[n], end = row_ptr[n + 1];
    int deg = end - beg;
    __shared__ int s_src[CHUNK];
    float acc = 0.f;
    for (int c0 = 0; c0 < deg; c0 += CHUNK) {
        int cn = min(CHUNK, deg - c0);
        __syncthreads();
        for (int i = tid; i < cn; i += 128)
            s_src[i] = col[beg + c0 + i] & 0x7fffffff;
        __syncthreads();
        int i = 0;
        for (; i + 8 <= cn; i += 8) {
            int ss[8]; float hv[8];
            #pragma unroll
            for (int u = 0; u < 8; ++u) ss[u] = s_src[i + u];
            #pragma unroll
            for (int u = 0; u < 8; ++u) hv[u] = Hin[(size_t)ss[u] * DD + tid];
            #pragma unroll
            for (int u = 0; u < 8; ++u) acc += hv[u];
        }
        for (; i < cn; ++i) acc += Hin[(size_t)s_src[i] * DD + tid];
    }
    acc -= Hin[(size_t)n * DD + tid];          // remove appended self-loop
    int cnt = deg - 1;
    float mean = acc / (float)((cnt > 0) ? cnt : 1);
    float val = mean + X[(size_t)n * DD + tid];
    Out[(size_t)n * DD + tid] = fmaxf(val, 0.f);
}

extern "C" void kernel_launch(void* const* d_in, const int* in_sizes, int n_in,
                              void* d_out, int out_size, void* d_ws, size_t ws_size,
                              hipStream_t stream) {
    const float* x    = (const float*)d_in[0];
    const int*   ei   = (const int*)d_in[1];
    const float* W1   = (const float*)d_in[2];
    const float* as1  = (const float*)d_in[3];
    const float* ad1  = (const float*)d_in[4];
    const float* b1   = (const float*)d_in[5];
    const float* ln1w = (const float*)d_in[6];
    const float* ln1b = (const float*)d_in[7];
    const float* W2   = (const float*)d_in[8];
    const float* as2  = (const float*)d_in[9];
    const float* ad2  = (const float*)d_in[10];
    const float* b2   = (const float*)d_in[11];
    const float* ln2w = (const float*)d_in[12];
    const float* ln2b = (const float*)d_in[13];
    float* out = (float*)d_out;

    char* p = (char*)d_ws;
    auto alloc = [&](size_t bytes) {
        void* r = (void*)p;
        p += (bytes + 255) & ~(size_t)255;
        return r;
    };
    int*    deg     = (int*)alloc((size_t)NN * 4);
    int*    row_ptr = (int*)alloc((size_t)(NN + 1) * 4);
    int*    cursor  = (int*)alloc((size_t)NN * 4);
    double* stats1  = (double*)alloc(16);
    double* stats2  = (double*)alloc(16);
    float2* pstats  = (float2*)alloc((size_t)NN * 8);
    int*    col     = (int*)alloc((size_t)EP * 4);
    float*  bufA    = (float*)alloc((size_t)NN * DD * 4);  // h1, later h2
    float*  bufB    = (float*)alloc((size_t)NN * DD * 4);  // out1/hln1, later out2/hln2
    float*  aS1     = (float*)alloc((size_t)NN * 2 * 4);
    float*  aD1     = (float*)alloc((size_t)NN * 2 * 4);
    float*  aS2     = (float*)alloc((size_t)NN * 4);
    float*  aD2     = (float*)alloc((size_t)NN * 4);

    hipMemsetAsync(deg, 0, (size_t)NN * 4, stream);

    hist_kernel<<<(EP + 255) / 256, 256, 0, stream>>>(ei, deg);
    scan_kernel<<<1, 1024, 0, stream>>>(deg, row_ptr, cursor);
    scatter_kernel<<<(EP + 255) / 256, 256, 0, stream>>>(ei, cursor, col);

    // layer 1: GATConv(128 -> 64, heads=2, concat) + graph-LN + relu
    gemm_attn<2><<<(NN + 3) / 4, 128, 0, stream>>>(x, W1, as1, ad1, bufA, aS1, aD1);
    gat_agg<2><<<NN, 128, 0, stream>>>(row_ptr, col, bufA, aS1, aD1, b1, bufB, pstats);
    reduce_stats_kernel<<<1, 1024, 0, stream>>>(pstats, stats1);
    ln_kernel<<<(NN * DD + 255) / 256, 256, 0, stream>>>(bufB, stats1, ln1w, ln1b, 1);

    // layer 2: GATConv(128 -> 128, heads=1) + graph-LN
    gemm_attn<1><<<(NN + 3) / 4, 128, 0, stream>>>(bufB, W2, as2, ad2, bufA, aS2, aD2);
    gat_agg<1><<<NN, 128, 0, stream>>>(row_ptr, col, bufA, aS2, aD2, b2, bufB, pstats);
    reduce_stats_kernel<<<1, 1024, 0, stream>>>(pstats, stats2);
    ln_kernel<<<(NN * DD + 255) / 256, 256, 0, stream>>>(bufB, stats2, ln2w, ln2b, 0);

    // SimpleConv mean over original edges + residual + relu
    simpleconv_kernel<<<NN, 128, 0, stream>>>(row_ptr, col, bufB, x, out);
}

// Round 4
// 511.247 us; speedup vs baseline: 5.7192x; 1.1680x over previous
//
#include <hip/hip_runtime.h>
#include <hip/hip_bf16.h>
#include <cstdint>
#include <cstddef>

#define NN 50000
#define EE 800000
#define EP (EE + NN)   // 850000 edges incl. appended self-loops
#define DD 128
#define NEG 0.2f
#define EPSL 1e-5f
#define CHUNK 512

typedef __hip_bfloat16 bf16;

__device__ inline float wave_reduce_sum(float v) {
    for (int off = 32; off; off >>= 1) v += __shfl_xor(v, off);
    return v;
}
__device__ inline float wave_reduce_max(float v) {
    for (int off = 32; off; off >>= 1) v = fmaxf(v, __shfl_xor(v, off));
    return v;
}

// ---------------- CSR build ----------------

__global__ __launch_bounds__(256) void hist_kernel(const int* __restrict__ ei,
                                                   int* __restrict__ deg) {
    int i = blockIdx.x * 256 + threadIdx.x;
    if (i >= EP) return;
    int dst = (i < EE) ? ei[EE + i] : (i - EE);
    atomicAdd(&deg[dst], 1);
}

// single-block exclusive scan over deg[0..NN) -> row_ptr, cursor (int4 + shuffle)
__global__ __launch_bounds__(1024) void scan_kernel(const int* __restrict__ deg,
                                                    int* __restrict__ row_ptr,
                                                    int* __restrict__ cursor) {
    __shared__ int wsum[16];
    __shared__ int carry_s;
    int tid = threadIdx.x, lane = tid & 63, wv = tid >> 6;  // 16 waves
    if (tid == 0) carry_s = 0;
    __syncthreads();
    for (int base = 0; base < NN; base += 4096) {
        int i4 = base + tid * 4;
        int4 v;
        if (i4 + 3 < NN) v = *(const int4*)&deg[i4];
        else {
            v.x = (i4 + 0 < NN) ? deg[i4 + 0] : 0;
            v.y = (i4 + 1 < NN) ? deg[i4 + 1] : 0;
            v.z = (i4 + 2 < NN) ? deg[i4 + 2] : 0;
            v.w = (i4 + 3 < NN) ? deg[i4 + 3] : 0;
        }
        int tsum = v.x + v.y + v.z + v.w;
        int x = tsum;
        for (int off = 1; off < 64; off <<= 1) {
            int t = __shfl_up(x, off);
            if (lane >= off) x += t;
        }
        if (lane == 63) wsum[wv] = x;
        __syncthreads();
        if (wv == 0) {
            int s = (lane < 16) ? wsum[lane] : 0;
            for (int off = 1; off < 16; off <<= 1) {
                int t = __shfl_up(s, off);
                if (lane >= off) s += t;
            }
            if (lane < 16) wsum[lane] = s;
        }
        __syncthreads();
        int waveoff = (wv == 0) ? 0 : wsum[wv - 1];
        int carry = carry_s;
        int o0 = carry + waveoff + x - tsum;
        int o1 = o0 + v.x, o2 = o1 + v.y, o3 = o2 + v.z;
        if (i4 + 3 < NN) {
            int4 o = make_int4(o0, o1, o2, o3);
            *(int4*)&row_ptr[i4] = o;
            *(int4*)&cursor[i4] = o;
        } else {
            if (i4 + 0 < NN) { row_ptr[i4 + 0] = o0; cursor[i4 + 0] = o0; }
            if (i4 + 1 < NN) { row_ptr[i4 + 1] = o1; cursor[i4 + 1] = o1; }
            if (i4 + 2 < NN) { row_ptr[i4 + 2] = o2; cursor[i4 + 2] = o2; }
            if (i4 + 3 < NN) { row_ptr[i4 + 3] = o3; cursor[i4 + 3] = o3; }
        }
        __syncthreads();
        if (tid == 0) carry_s += wsum[15];
        __syncthreads();
    }
    if (tid == 0) row_ptr[NN] = carry_s;
}

__global__ __launch_bounds__(256) void scatter_kernel(const int* __restrict__ ei,
                                                      int* __restrict__ cursor,
                                                      int* __restrict__ col) {
    int i = blockIdx.x * 256 + threadIdx.x;
    if (i >= EP) return;
    int s, dst; unsigned flag;
    if (i < EE) { s = ei[i]; dst = ei[EE + i]; flag = 0u; }
    else        { s = i - EE; dst = s; flag = 0x80000000u; }  // appended self-loop
    int pos = atomicAdd(&cursor[dst], 1);
    col[pos] = (int)((unsigned)s | flag);
}

// ---------------- GEMM (+optional fused LN1+relu on input) + attention dots ----------------
// 8 rows per block (50000 = 8*6250 exactly); H output stored bf16 (it is only ever gathered)
template <int H, bool LN>
__global__ __launch_bounds__(128) void gemm_attn(const float* __restrict__ X,
                                                 const float* __restrict__ W,
                                                 const float* __restrict__ att_s,
                                                 const float* __restrict__ att_d,
                                                 const double* __restrict__ stats,
                                                 const float* __restrict__ lnw,
                                                 const float* __restrict__ lnb,
                                                 bf16* __restrict__ Hout,
                                                 float* __restrict__ a_src,
                                                 float* __restrict__ a_dst) {
    const int ROWS = 8;
    int tid = threadIdx.x, lane = tid & 63, wave = tid >> 6;
    __shared__ float xs[ROWS][DD];
    __shared__ float ps_s[ROWS][2], ps_d[ROWS][2];
    int row0 = blockIdx.x * ROWS;

    float mean = 0.f, inv = 1.f, wc = 1.f, bc = 0.f;
    if (LN) {
        const double M = (double)NN * DD;
        double mean_d = stats[0] / M;
        double var_d = stats[1] / M - mean_d * mean_d;
        mean = (float)mean_d;
        inv = rsqrtf((float)var_d + EPSL);
        wc = lnw[tid]; bc = lnb[tid];
    }
    #pragma unroll
    for (int r = 0; r < ROWS; ++r) {
        int row = row0 + r;
        float v = (row < NN) ? X[(size_t)row * DD + tid] : 0.f;
        if (LN) v = fmaxf((v - mean) * inv * wc + bc, 0.f);
        xs[r][tid] = v;
    }
    __syncthreads();
    float acc[ROWS] = {0.f};
    for (int k = 0; k < DD; ++k) {
        float w = W[k * DD + tid];
        #pragma unroll
        for (int r = 0; r < ROWS; ++r) acc[r] = fmaf(xs[r][k], w, acc[r]);
    }
    float as = att_s[tid], ad = att_d[tid];
    #pragma unroll
    for (int r = 0; r < ROWS; ++r) {
        int row = row0 + r;
        if (row >= NN) break;
        Hout[(size_t)row * DD + tid] = (bf16)acc[r];
        float psum = wave_reduce_sum(acc[r] * as);
        float pdum = wave_reduce_sum(acc[r] * ad);
        if (lane == 0) { ps_s[r][wave] = psum; ps_d[r][wave] = pdum; }
    }
    __syncthreads();
    if (tid < ROWS) {
        int row = row0 + tid;
        if (row < NN) {
            if (H == 2) {
                a_src[row * 2 + 0] = ps_s[tid][0];
                a_src[row * 2 + 1] = ps_s[tid][1];
                a_dst[row * 2 + 0] = ps_d[tid][0];
                a_dst[row * 2 + 1] = ps_d[tid][1];
            } else {
                a_src[row] = ps_s[tid][0] + ps_s[tid][1];
                a_dst[row] = ps_d[tid][0] + ps_d[tid][1];
            }
        }
    }
}

// ---------------- fused GAT softmax + aggregate (+per-block LN partials) ----------------
// one block (128 threads) per destination node; wave == head for H=2
// OT = float (out read coalesced later) or bf16 (out only ever gathered)
template <int H, typename OT>
__global__ __launch_bounds__(128) void gat_agg(const int* __restrict__ row_ptr,
                                               const int* __restrict__ col,
                                               const bf16* __restrict__ Hin,
                                               const float* __restrict__ a_src,
                                               const float* __restrict__ a_dst,
                                               const float* __restrict__ bias,
                                               OT* __restrict__ Out,
                                               float2* __restrict__ pstats) {
    int n = blockIdx.x;
    int tid = threadIdx.x, lane = tid & 63, wave = tid >> 6;
    int beg = row_ptr[n], end = row_ptr[n + 1];
    int deg = end - beg;

    __shared__ int   s_src[CHUNK];
    __shared__ float s_w[H][CHUNK];
    __shared__ float s_red[8];

    float ad0 = a_dst[n * H + 0];
    float ad1 = (H == 2) ? a_dst[n * H + 1] : 0.f;

    // ---- phase 1: global max per head ----
    float m0 = -1e30f, m1 = -1e30f;
    for (int i = tid; i < deg; i += 128) {
        int s = col[beg + i] & 0x7fffffff;
        if (H == 2) {
            float2 av = *(const float2*)&a_src[s * 2];
            float e0 = av.x + ad0; e0 = (e0 > 0.f) ? e0 : NEG * e0;
            float e1 = av.y + ad1; e1 = (e1 > 0.f) ? e1 : NEG * e1;
            m0 = fmaxf(m0, e0); m1 = fmaxf(m1, e1);
        } else {
            float e0 = a_src[s] + ad0; e0 = (e0 > 0.f) ? e0 : NEG * e0;
            m0 = fmaxf(m0, e0);
        }
    }
    m0 = wave_reduce_max(m0);
    if (H == 2) m1 = wave_reduce_max(m1);
    if (lane == 0) { s_red[wave] = m0; if (H == 2) s_red[2 + wave] = m1; }
    __syncthreads();
    m0 = fmaxf(s_red[0], s_red[1]);
    if (H == 2) m1 = fmaxf(s_red[2], s_red[3]);

    // ---- phase 2: chunked stage + accumulate (bf16 feature gathers) ----
    float accv = 0.f;
    float dloc0 = 0.f, dloc1 = 0.f;
    for (int c0 = 0; c0 < deg; c0 += CHUNK) {
        int cn = min(CHUNK, deg - c0);
        __syncthreads();
        for (int i = tid; i < cn; i += 128) {
            int s = col[beg + c0 + i] & 0x7fffffff;
            s_src[i] = s;
            if (H == 2) {
                float2 av = *(const float2*)&a_src[s * 2];
                float e0 = av.x + ad0; e0 = (e0 > 0.f) ? e0 : NEG * e0;
                float e1 = av.y + ad1; e1 = (e1 > 0.f) ? e1 : NEG * e1;
                float w0 = __expf(e0 - m0), w1 = __expf(e1 - m1);
                s_w[0][i] = w0; s_w[1][i] = w1;
                dloc0 += w0; dloc1 += w1;
            } else {
                float e0 = a_src[s] + ad0; e0 = (e0 > 0.f) ? e0 : NEG * e0;
                float w0 = __expf(e0 - m0);
                s_w[0][i] = w0;
                dloc0 += w0;
            }
        }
        __syncthreads();
        const float* wrow = (H == 2) ? s_w[wave] : s_w[0];
        int i = 0;
        for (; i + 8 <= cn; i += 8) {
            int ss[8]; float ww[8], hv[8];
            #pragma unroll
            for (int u = 0; u < 8; ++u) { ss[u] = s_src[i + u]; ww[u] = wrow[i + u]; }
            #pragma unroll
            for (int u = 0; u < 8; ++u) { hv[u] = (float)Hin[(size_t)ss[u] * DD + tid]; }
            #pragma unroll
            for (int u = 0; u < 8; ++u) { accv = fmaf(ww[u], hv[u], accv); }
        }
        for (; i < cn; ++i) accv = fmaf(wrow[i], (float)Hin[(size_t)s_src[i] * DD + tid], accv);
    }

    // ---- denominator across block ----
    float d0 = wave_reduce_sum(dloc0);
    float d1 = (H == 2) ? wave_reduce_sum(dloc1) : 0.f;
    __syncthreads();
    if (lane == 0) { s_red[wave] = d0; if (H == 2) s_red[2 + wave] = d1; }
    __syncthreads();
    float den;
    if (H == 2) den = (wave == 0) ? (s_red[0] + s_red[1]) : (s_red[2] + s_red[3]);
    else        den = s_red[0] + s_red[1];

    float out = accv / (den + 1e-16f) + bias[tid];
    Out[(size_t)n * DD + tid] = (OT)out;

    // LN (graph mode) partials -> per-block store (no same-address atomics)
    float s1 = wave_reduce_sum(out);
    float s2 = wave_reduce_sum(out * out);
    __shared__ float red2[4];
    if (lane == 0) { red2[wave] = s1; red2[2 + wave] = s2; }
    __syncthreads();
    if (tid == 0) {
        pstats[n] = make_float2(red2[0] + red2[1], red2[2] + red2[3]);
    }
}

// ---------------- deterministic single-block reduce of per-node LN partials ----------------
__global__ __launch_bounds__(1024) void reduce_stats_kernel(const float2* __restrict__ pstats,
                                                            double* __restrict__ stats) {
    int tid = threadIdx.x, lane = tid & 63, wv = tid >> 6;
    double s1 = 0.0, s2 = 0.0;
    for (int i = tid; i < NN; i += 1024) {
        float2 v = pstats[i];
        s1 += (double)v.x; s2 += (double)v.y;
    }
    for (int off = 32; off; off >>= 1) {
        s1 += __shfl_xor(s1, off);
        s2 += __shfl_xor(s2, off);
    }
    __shared__ double w1[16], w2[16];
    if (lane == 0) { w1[wv] = s1; w2[wv] = s2; }
    __syncthreads();
    if (tid == 0) {
        double a = 0.0, b = 0.0;
        for (int i = 0; i < 16; ++i) { a += w1[i]; b += w2[i]; }
        stats[0] = a; stats[1] = b;
    }
}

// ---------------- SimpleConv(mean, ORIGINAL edges) + fused LN2 affine + residual + relu ----
// LN2 is affine => commutes with the mean: mean(ln2(h_s)) = affine(mean(h_s)) when cnt>0.
__global__ __launch_bounds__(128) void simpleconv_kernel(const int* __restrict__ row_ptr,
                                                         const int* __restrict__ col,
                                                         const bf16* __restrict__ Hin,
                                                         const float* __restrict__ X,
                                                         const double* __restrict__ stats,
                                                         const float* __restrict__ lnw,
                                                         const float* __restrict__ lnb,
                                                         float* __restrict__ Out) {
    int n = blockIdx.x, tid = threadIdx.x;
    int beg = row_ptr[n], end = row_ptr[n + 1];
    int deg = end - beg;
    __shared__ int s_src[CHUNK];
    const double M = (double)NN * DD;
    double mean_d = stats[0] / M;
    double var_d = stats[1] / M - mean_d * mean_d;
    float mean2 = (float)mean_d;
    float inv2 = rsqrtf((float)var_d + EPSL);

    float acc = 0.f;
    for (int c0 = 0; c0 < deg; c0 += CHUNK) {
        int cn = min(CHUNK, deg - c0);
        __syncthreads();
        for (int i = tid; i < cn; i += 128)
            s_src[i] = col[beg + c0 + i] & 0x7fffffff;
        __syncthreads();
        int i = 0;
        for (; i + 8 <= cn; i += 8) {
            int ss[8]; float hv[8];
            #pragma unroll
            for (int u = 0; u < 8; ++u) ss[u] = s_src[i + u];
            #pragma unroll
            for (int u = 0; u < 8; ++u) hv[u] = (float)Hin[(size_t)ss[u] * DD + tid];
            #pragma unroll
            for (int u = 0; u < 8; ++u) acc += hv[u];
        }
        for (; i < cn; ++i) acc += (float)Hin[(size_t)s_src[i] * DD + tid];
    }
    acc -= (float)Hin[(size_t)n * DD + tid];   // remove appended self-loop (exact cancel)
    int cnt = deg - 1;
    float val;
    if (cnt > 0) {
        float meanagg = acc / (float)cnt;
        val = (meanagg - mean2) * inv2 * lnw[tid] + lnb[tid];
    } else {
        val = 0.f;                              // ref: agg=0, cnt clamped to 1 -> 0
    }
    val += X[(size_t)n * DD + tid];
    Out[(size_t)n * DD + tid] = fmaxf(val, 0.f);
}

extern "C" void kernel_launch(void* const* d_in, const int* in_sizes, int n_in,
                              void* d_out, int out_size, void* d_ws, size_t ws_size,
                              hipStream_t stream) {
    const float* x    = (const float*)d_in[0];
    const int*   ei   = (const int*)d_in[1];
    const float* W1   = (const float*)d_in[2];
    const float* as1  = (const float*)d_in[3];
    const float* ad1  = (const float*)d_in[4];
    const float* b1   = (const float*)d_in[5];
    const float* ln1w = (const float*)d_in[6];
    const float* ln1b = (const float*)d_in[7];
    const float* W2   = (const float*)d_in[8];
    const float* as2  = (const float*)d_in[9];
    const float* ad2  = (const float*)d_in[10];
    const float* b2   = (const float*)d_in[11];
    const float* ln2w = (const float*)d_in[12];
    const float* ln2b = (const float*)d_in[13];
    float* out = (float*)d_out;

    char* p = (char*)d_ws;
    auto alloc = [&](size_t bytes) {
        void* r = (void*)p;
        p += (bytes + 255) & ~(size_t)255;
        return r;
    };
    int*    deg     = (int*)alloc((size_t)NN * 4);
    int*    row_ptr = (int*)alloc((size_t)(NN + 1) * 4);
    int*    cursor  = (int*)alloc((size_t)NN * 4);
    double* stats1  = (double*)alloc(16);
    double* stats2  = (double*)alloc(16);
    float2* pstats  = (float2*)alloc((size_t)NN * 8);
    int*    col     = (int*)alloc((size_t)EP * 4);
    bf16*   bufH    = (bf16*)alloc((size_t)NN * DD * 2);   // h1, later h2 (bf16, gathered)
    float*  bufF    = (float*)alloc((size_t)NN * DD * 4);  // out1 (fp32); later out2 (bf16 alias)
    bf16*   out2    = (bf16*)bufF;                         // alias: out1 dead before out2 written
    float*  aS1     = (float*)alloc((size_t)NN * 2 * 4);
    float*  aD1     = (float*)alloc((size_t)NN * 2 * 4);
    float*  aS2     = (float*)alloc((size_t)NN * 4);
    float*  aD2     = (float*)alloc((size_t)NN * 4);

    hipMemsetAsync(deg, 0, (size_t)NN * 4, stream);

    hist_kernel<<<(EP + 255) / 256, 256, 0, stream>>>(ei, deg);
    scan_kernel<<<1, 1024, 0, stream>>>(deg, row_ptr, cursor);
    scatter_kernel<<<(EP + 255) / 256, 256, 0, stream>>>(ei, cursor, col);

    // layer 1: GATConv(128 -> 64, heads=2, concat); LN1+relu deferred into next gemm
    gemm_attn<2, false><<<(NN + 7) / 8, 128, 0, stream>>>(x, W1, as1, ad1,
                                                          nullptr, nullptr, nullptr,
                                                          bufH, aS1, aD1);
    gat_agg<2, float><<<NN, 128, 0, stream>>>(row_ptr, col, bufH, aS1, aD1, b1, bufF, pstats);
    reduce_stats_kernel<<<1, 1024, 0, stream>>>(pstats, stats1);

    // layer 2: GATConv(128 -> 128, heads=1), input = relu(ln1(out1)) fused into gemm
    gemm_attn<1, true><<<(NN + 7) / 8, 128, 0, stream>>>(bufF, W2, as2, ad2,
                                                         stats1, ln1w, ln1b,
                                                         bufH, aS2, aD2);
    gat_agg<1, bf16><<<NN, 128, 0, stream>>>(row_ptr, col, bufH, aS2, aD2, b2, out2, pstats);
    reduce_stats_kernel<<<1, 1024, 0, stream>>>(pstats, stats2);

    // SimpleConv mean over original edges + LN2 affine + residual + relu (fused)
    simpleconv_kernel<<<NN, 128, 0, stream>>>(row_ptr, col, out2, x,
                                              stats2, ln2w, ln2b, out);
}

// Round 5
// 472.106 us; speedup vs baseline: 6.1933x; 1.0829x over previous
//
#include <hip/hip_runtime.h>
#include <hip/hip_bf16.h>
#include <cstdint>
#include <cstddef>

#define NN 50000
#define EE 800000
#define EP (EE + NN)   // 850000 edges incl. appended self-loops
#define DD 128
#define NEG 0.2f
#define EPSL 1e-5f
#define CHUNK 512

typedef __hip_bfloat16 bf16;

__device__ inline float wave_reduce_sum(float v) {
    for (int off = 32; off; off >>= 1) v += __shfl_xor(v, off);
    return v;
}
__device__ inline float wave_reduce_max(float v) {
    for (int off = 32; off; off >>= 1) v = fmaxf(v, __shfl_xor(v, off));
    return v;
}
__device__ inline float bflo(unsigned u) { return __uint_as_float(u << 16); }
__device__ inline float bfhi(unsigned u) { return __uint_as_float(u & 0xffff0000u); }

__device__ inline void store4(float* Out, size_t idx, float4 v) {
    *(float4*)&Out[idx] = v;
}
__device__ inline void store4(bf16* Out, size_t idx, float4 v) {
    union { bf16 b[4]; ushort4 u; } cv;
    cv.b[0] = (bf16)v.x; cv.b[1] = (bf16)v.y; cv.b[2] = (bf16)v.z; cv.b[3] = (bf16)v.w;
    *(ushort4*)&Out[idx] = cv.u;
}

// ---------------- CSR build ----------------

__global__ __launch_bounds__(256) void hist_kernel(const int* __restrict__ ei,
                                                   int* __restrict__ deg) {
    int i = blockIdx.x * 256 + threadIdx.x;
    if (i >= EP) return;
    int dst = (i < EE) ? ei[EE + i] : (i - EE);
    atomicAdd(&deg[dst], 1);
}

// single-block exclusive scan over deg[0..NN) -> row_ptr, cursor (int4 + shuffle)
__global__ __launch_bounds__(1024) void scan_kernel(const int* __restrict__ deg,
                                                    int* __restrict__ row_ptr,
                                                    int* __restrict__ cursor) {
    __shared__ int wsum[16];
    __shared__ int carry_s;
    int tid = threadIdx.x, lane = tid & 63, wv = tid >> 6;  // 16 waves
    if (tid == 0) carry_s = 0;
    __syncthreads();
    for (int base = 0; base < NN; base += 4096) {
        int i4 = base + tid * 4;
        int4 v;
        if (i4 + 3 < NN) v = *(const int4*)&deg[i4];
        else {
            v.x = (i4 + 0 < NN) ? deg[i4 + 0] : 0;
            v.y = (i4 + 1 < NN) ? deg[i4 + 1] : 0;
            v.z = (i4 + 2 < NN) ? deg[i4 + 2] : 0;
            v.w = (i4 + 3 < NN) ? deg[i4 + 3] : 0;
        }
        int tsum = v.x + v.y + v.z + v.w;
        int x = tsum;
        for (int off = 1; off < 64; off <<= 1) {
            int t = __shfl_up(x, off);
            if (lane >= off) x += t;
        }
        if (lane == 63) wsum[wv] = x;
        __syncthreads();
        if (wv == 0) {
            int s = (lane < 16) ? wsum[lane] : 0;
            for (int off = 1; off < 16; off <<= 1) {
                int t = __shfl_up(s, off);
                if (lane >= off) s += t;
            }
            if (lane < 16) wsum[lane] = s;
        }
        __syncthreads();
        int waveoff = (wv == 0) ? 0 : wsum[wv - 1];
        int carry = carry_s;
        int o0 = carry + waveoff + x - tsum;
        int o1 = o0 + v.x, o2 = o1 + v.y, o3 = o2 + v.z;
        if (i4 + 3 < NN) {
            int4 o = make_int4(o0, o1, o2, o3);
            *(int4*)&row_ptr[i4] = o;
            *(int4*)&cursor[i4] = o;
        } else {
            if (i4 + 0 < NN) { row_ptr[i4 + 0] = o0; cursor[i4 + 0] = o0; }
            if (i4 + 1 < NN) { row_ptr[i4 + 1] = o1; cursor[i4 + 1] = o1; }
            if (i4 + 2 < NN) { row_ptr[i4 + 2] = o2; cursor[i4 + 2] = o2; }
            if (i4 + 3 < NN) { row_ptr[i4 + 3] = o3; cursor[i4 + 3] = o3; }
        }
        __syncthreads();
        if (tid == 0) carry_s += wsum[15];
        __syncthreads();
    }
    if (tid == 0) row_ptr[NN] = carry_s;
}

__global__ __launch_bounds__(256) void scatter_kernel(const int* __restrict__ ei,
                                                      int* __restrict__ cursor,
                                                      int* __restrict__ col) {
    int i = blockIdx.x * 256 + threadIdx.x;
    if (i >= EP) return;
    int s, dst; unsigned flag;
    if (i < EE) { s = ei[i]; dst = ei[EE + i]; flag = 0u; }
    else        { s = i - EE; dst = s; flag = 0x80000000u; }  // appended self-loop
    int pos = atomicAdd(&cursor[dst], 1);
    col[pos] = (int)((unsigned)s | flag);
}

// ---------------- GEMM (+optional fused LN1+relu on input) + attention dots ----------------
template <int H, bool LN>
__global__ __launch_bounds__(128) void gemm_attn(const float* __restrict__ X,
                                                 const float* __restrict__ W,
                                                 const float* __restrict__ att_s,
                                                 const float* __restrict__ att_d,
                                                 const double* __restrict__ stats,
                                                 const float* __restrict__ lnw,
                                                 const float* __restrict__ lnb,
                                                 bf16* __restrict__ Hout,
                                                 float* __restrict__ a_src,
                                                 float* __restrict__ a_dst) {
    const int ROWS = 8;
    int tid = threadIdx.x, lane = tid & 63, wave = tid >> 6;
    __shared__ float xs[ROWS][DD];
    __shared__ float ps_s[ROWS][2], ps_d[ROWS][2];
    int row0 = blockIdx.x * ROWS;

    float mean = 0.f, inv = 1.f, wc = 1.f, bc = 0.f;
    if (LN) {
        const double M = (double)NN * DD;
        double mean_d = stats[0] / M;
        double var_d = stats[1] / M - mean_d * mean_d;
        mean = (float)mean_d;
        inv = rsqrtf((float)var_d + EPSL);
        wc = lnw[tid]; bc = lnb[tid];
    }
    #pragma unroll
    for (int r = 0; r < ROWS; ++r) {
        int row = row0 + r;
        float v = (row < NN) ? X[(size_t)row * DD + tid] : 0.f;
        if (LN) v = fmaxf((v - mean) * inv * wc + bc, 0.f);
        xs[r][tid] = v;
    }
    __syncthreads();
    float acc[ROWS] = {0.f};
    for (int k = 0; k < DD; ++k) {
        float w = W[k * DD + tid];
        #pragma unroll
        for (int r = 0; r < ROWS; ++r) acc[r] = fmaf(xs[r][k], w, acc[r]);
    }
    float as = att_s[tid], ad = att_d[tid];
    #pragma unroll
    for (int r = 0; r < ROWS; ++r) {
        int row = row0 + r;
        if (row >= NN) break;
        Hout[(size_t)row * DD + tid] = (bf16)acc[r];
        float psum = wave_reduce_sum(acc[r] * as);
        float pdum = wave_reduce_sum(acc[r] * ad);
        if (lane == 0) { ps_s[r][wave] = psum; ps_d[r][wave] = pdum; }
    }
    __syncthreads();
    if (tid < ROWS) {
        int row = row0 + tid;
        if (row < NN) {
            if (H == 2) {
                a_src[row * 2 + 0] = ps_s[tid][0];
                a_src[row * 2 + 1] = ps_s[tid][1];
                a_dst[row * 2 + 0] = ps_d[tid][0];
                a_dst[row * 2 + 1] = ps_d[tid][1];
            } else {
                a_src[row] = ps_s[tid][0] + ps_s[tid][1];
                a_dst[row] = ps_d[tid][0] + ps_d[tid][1];
            }
        }
    }
}

// ---------------- fused GAT online-softmax + aggregate (+per-block LN partials) ------------
// one block (128 threads) per dst node. 4 half-waves each own one edge at a time;
// each lane owns 4 consecutive channels (uint2 = 4 bf16 per gather).
template <int H, typename OT>
__global__ __launch_bounds__(128) void gat_agg(const int* __restrict__ row_ptr,
                                               const int* __restrict__ col,
                                               const bf16* __restrict__ Hin,
                                               const float* __restrict__ a_src,
                                               const float* __restrict__ a_dst,
                                               const float* __restrict__ bias,
                                               OT* __restrict__ Out,
                                               float2* __restrict__ pstats) {
    int n = blockIdx.x;
    int tid = threadIdx.x, lane = tid & 63, wave = tid >> 6;
    int hw = tid >> 5;            // half-wave 0..3
    int sl = lane & 31;           // sub-lane in half-wave
    int c0 = sl * 4;              // 4 channels per lane
    const int head4 = (H == 2) ? (sl >> 4) : 0;  // head of this lane's channels

    int beg = row_ptr[n], end = row_ptr[n + 1];
    int deg = end - beg;

    __shared__ int   s_src[CHUNK];
    __shared__ float s_w[H][CHUNK];
    __shared__ float s_red[8];
    __shared__ float s_acc[2][DD];

    float ad0 = a_dst[n * H + 0];
    float ad1 = (H == 2) ? a_dst[n * H + 1] : 0.f;

    const ushort* Hp = (const ushort*)Hin + c0;

    float m_run0 = -1e30f, m_run1 = -1e30f;
    float dloc0 = 0.f, dloc1 = 0.f;
    float acc[4] = {0.f, 0.f, 0.f, 0.f};

    for (int cbase = 0; cbase < deg; cbase += CHUNK) {
        int cn = min(CHUNK, deg - cbase);
        __syncthreads();  // protect LDS reuse across chunks
        // ---- stage raw scores + chunk max ----
        float mc0 = -1e30f, mc1 = -1e30f;
        for (int i = tid; i < cn; i += 128) {
            int s = col[beg + cbase + i] & 0x7fffffff;
            s_src[i] = s;
            if (H == 2) {
                float2 av = *(const float2*)&a_src[s * 2];
                float e0 = av.x + ad0; e0 = (e0 > 0.f) ? e0 : NEG * e0;
                float e1 = av.y + ad1; e1 = (e1 > 0.f) ? e1 : NEG * e1;
                s_w[0][i] = e0; s_w[1][i] = e1;
                mc0 = fmaxf(mc0, e0); mc1 = fmaxf(mc1, e1);
            } else {
                float e0 = a_src[s] + ad0; e0 = (e0 > 0.f) ? e0 : NEG * e0;
                s_w[0][i] = e0;
                mc0 = fmaxf(mc0, e0);
            }
        }
        mc0 = wave_reduce_max(mc0);
        if (H == 2) mc1 = wave_reduce_max(mc1);
        if (lane == 0) { s_red[wave] = mc0; if (H == 2) s_red[2 + wave] = mc1; }
        __syncthreads();
        mc0 = fmaxf(s_red[0], s_red[1]);
        if (H == 2) mc1 = fmaxf(s_red[2], s_red[3]);
        // ---- online-softmax rescale ----
        float mn0 = fmaxf(m_run0, mc0);
        float mn1 = (H == 2) ? fmaxf(m_run1, mc1) : 0.f;
        float sc0 = __expf(m_run0 - mn0);
        float sc1 = (H == 2) ? __expf(m_run1 - mn1) : 0.f;
        dloc0 *= sc0;
        if (H == 2) dloc1 *= sc1;
        float scA = (H == 2 && head4 == 1) ? sc1 : sc0;
        #pragma unroll
        for (int j = 0; j < 4; ++j) acc[j] *= scA;
        m_run0 = mn0; m_run1 = mn1;
        // ---- convert scores -> exp weights (each thread owns its staged slots) ----
        for (int i = tid; i < cn; i += 128) {
            float w0 = __expf(s_w[0][i] - mn0);
            s_w[0][i] = w0; dloc0 += w0;
            if (H == 2) {
                float w1 = __expf(s_w[1][i] - mn1);
                s_w[1][i] = w1; dloc1 += w1;
            }
        }
        __syncthreads();
        // ---- accumulate: half-wave hw takes edges hw, hw+4, ... ----
        const float* wrow = s_w[head4];
        int i = hw;
        for (; i + 12 < cn; i += 16) {
            int a0 = s_src[i], a1 = s_src[i + 4], a2 = s_src[i + 8], a3 = s_src[i + 12];
            float w0 = wrow[i], w1 = wrow[i + 4], w2 = wrow[i + 8], w3 = wrow[i + 12];
            uint2 h0 = *(const uint2*)(Hp + (size_t)a0 * DD);
            uint2 h1 = *(const uint2*)(Hp + (size_t)a1 * DD);
            uint2 h2 = *(const uint2*)(Hp + (size_t)a2 * DD);
            uint2 h3 = *(const uint2*)(Hp + (size_t)a3 * DD);
            acc[0] = fmaf(w0, bflo(h0.x), acc[0]); acc[1] = fmaf(w0, bfhi(h0.x), acc[1]);
            acc[2] = fmaf(w0, bflo(h0.y), acc[2]); acc[3] = fmaf(w0, bfhi(h0.y), acc[3]);
            acc[0] = fmaf(w1, bflo(h1.x), acc[0]); acc[1] = fmaf(w1, bfhi(h1.x), acc[1]);
            acc[2] = fmaf(w1, bflo(h1.y), acc[2]); acc[3] = fmaf(w1, bfhi(h1.y), acc[3]);
            acc[0] = fmaf(w2, bflo(h2.x), acc[0]); acc[1] = fmaf(w2, bfhi(h2.x), acc[1]);
            acc[2] = fmaf(w2, bflo(h2.y), acc[2]); acc[3] = fmaf(w2, bfhi(h2.y), acc[3]);
            acc[0] = fmaf(w3, bflo(h3.x), acc[0]); acc[1] = fmaf(w3, bfhi(h3.x), acc[1]);
            acc[2] = fmaf(w3, bflo(h3.y), acc[2]); acc[3] = fmaf(w3, bfhi(h3.y), acc[3]);
        }
        for (; i < cn; i += 4) {
            int s = s_src[i];
            float w = wrow[i];
            uint2 hv = *(const uint2*)(Hp + (size_t)s * DD);
            acc[0] = fmaf(w, bflo(hv.x), acc[0]); acc[1] = fmaf(w, bfhi(hv.x), acc[1]);
            acc[2] = fmaf(w, bflo(hv.y), acc[2]); acc[3] = fmaf(w, bfhi(hv.y), acc[3]);
        }
    }

    // ---- combine half-waves within wave, then across waves via LDS ----
    #pragma unroll
    for (int j = 0; j < 4; ++j) acc[j] += __shfl_xor(acc[j], 32);
    if (lane < 32) *(float4*)&s_acc[wave][c0] = make_float4(acc[0], acc[1], acc[2], acc[3]);

    float d0 = wave_reduce_sum(dloc0);
    float d1 = (H == 2) ? wave_reduce_sum(dloc1) : 0.f;
    if (lane == 0) { s_red[wave] = d0; if (H == 2) s_red[2 + wave] = d1; }
    __syncthreads();
    float den_h0 = s_red[0] + s_red[1];
    float den_h1 = (H == 2) ? (s_red[2] + s_red[3]) : 0.f;

    if (wave == 0 && lane < 32) {
        float den = (H == 2 && head4 == 1) ? den_h1 : den_h0;
        float rinv = 1.f / (den + 1e-16f);
        float4 bi = *(const float4*)&bias[c0];
        float4 o;
        o.x = (s_acc[0][c0 + 0] + s_acc[1][c0 + 0]) * rinv + bi.x;
        o.y = (s_acc[0][c0 + 1] + s_acc[1][c0 + 1]) * rinv + bi.y;
        o.z = (s_acc[0][c0 + 2] + s_acc[1][c0 + 2]) * rinv + bi.z;
        o.w = (s_acc[0][c0 + 3] + s_acc[1][c0 + 3]) * rinv + bi.w;
        store4(Out, (size_t)n * DD + c0, o);
        // LN partials over the node's 128 outputs
        float t1 = o.x + o.y + o.z + o.w;
        float t2 = o.x * o.x + o.y * o.y + o.z * o.z + o.w * o.w;
        for (int off = 16; off; off >>= 1) {
            t1 += __shfl_xor(t1, off);
            t2 += __shfl_xor(t2, off);
        }
        if (lane == 0) pstats[n] = make_float2(t1, t2);
    }
}

// ---------------- deterministic single-block reduce of per-node LN partials ----------------
__global__ __launch_bounds__(1024) void reduce_stats_kernel(const float2* __restrict__ pstats,
                                                            double* __restrict__ stats) {
    int tid = threadIdx.x, lane = tid & 63, wv = tid >> 6;
    double s1 = 0.0, s2 = 0.0;
    for (int i = tid; i < NN; i += 1024) {
        float2 v = pstats[i];
        s1 += (double)v.x; s2 += (double)v.y;
    }
    for (int off = 32; off; off >>= 1) {
        s1 += __shfl_xor(s1, off);
        s2 += __shfl_xor(s2, off);
    }
    __shared__ double w1[16], w2[16];
    if (lane == 0) { w1[wv] = s1; w2[wv] = s2; }
    __syncthreads();
    if (tid == 0) {
        double a = 0.0, b = 0.0;
        for (int i = 0; i < 16; ++i) { a += w1[i]; b += w2[i]; }
        stats[0] = a; stats[1] = b;
    }
}

// ---------------- SimpleConv(mean, ORIGINAL edges) + fused LN2 affine + residual + relu ----
__global__ __launch_bounds__(128) void simpleconv_kernel(const int* __restrict__ row_ptr,
                                                         const int* __restrict__ col,
                                                         const bf16* __restrict__ Hin,
                                                         const float* __restrict__ X,
                                                         const double* __restrict__ stats,
                                                         const float* __restrict__ lnw,
                                                         const float* __restrict__ lnb,
                                                         float* __restrict__ Out) {
    int n = blockIdx.x;
    int tid = threadIdx.x, lane = tid & 63, wave = tid >> 6;
    int hw = tid >> 5, sl = lane & 31, c0 = sl * 4;
    int beg = row_ptr[n], end = row_ptr[n + 1];
    int deg = end - beg;
    __shared__ int s_src[CHUNK];
    __shared__ float s_acc[2][DD];
    const ushort* Hp = (const ushort*)Hin + c0;

    float acc[4] = {0.f, 0.f, 0.f, 0.f};
    for (int cbase = 0; cbase < deg; cbase += CHUNK) {
        int cn = min(CHUNK, deg - cbase);
        __syncthreads();
        for (int i = tid; i < cn; i += 128)
            s_src[i] = col[beg + cbase + i] & 0x7fffffff;
        __syncthreads();
        int i = hw;
        for (; i + 12 < cn; i += 16) {
            int a0 = s_src[i], a1 = s_src[i + 4], a2 = s_src[i + 8], a3 = s_src[i + 12];
            uint2 h0 = *(const uint2*)(Hp + (size_t)a0 * DD);
            uint2 h1 = *(const uint2*)(Hp + (size_t)a1 * DD);
            uint2 h2 = *(const uint2*)(Hp + (size_t)a2 * DD);
            uint2 h3 = *(const uint2*)(Hp + (size_t)a3 * DD);
            acc[0] += bflo(h0.x) + bflo(h1.x) + bflo(h2.x) + bflo(h3.x);
            acc[1] += bfhi(h0.x) + bfhi(h1.x) + bfhi(h2.x) + bfhi(h3.x);
            acc[2] += bflo(h0.y) + bflo(h1.y) + bflo(h2.y) + bflo(h3.y);
            acc[3] += bfhi(h0.y) + bfhi(h1.y) + bfhi(h2.y) + bfhi(h3.y);
        }
        for (; i < cn; i += 4) {
            uint2 hv = *(const uint2*)(Hp + (size_t)s_src[i] * DD);
            acc[0] += bflo(hv.x); acc[1] += bfhi(hv.x);
            acc[2] += bflo(hv.y); acc[3] += bfhi(hv.y);
        }
    }
    #pragma unroll
    for (int j = 0; j < 4; ++j) acc[j] += __shfl_xor(acc[j], 32);
    if (lane < 32) *(float4*)&s_acc[wave][c0] = make_float4(acc[0], acc[1], acc[2], acc[3]);
    __syncthreads();
    if (wave == 0 && lane < 32) {
        const double M = (double)NN * DD;
        double mean_d = stats[0] / M;
        double var_d = stats[1] / M - mean_d * mean_d;
        float mean2 = (float)mean_d;
        float inv2 = rsqrtf((float)var_d + EPSL);
        uint2 selfv = *(const uint2*)(Hp + (size_t)n * DD);  // appended self-loop row
        float sv[4] = {bflo(selfv.x), bfhi(selfv.x), bflo(selfv.y), bfhi(selfv.y)};
        int cnt = deg - 1;
        float rc = 1.f / (float)((cnt > 0) ? cnt : 1);
        float4 xr = *(const float4*)&X[(size_t)n * DD + c0];
        float4 o;
        float a0 = s_acc[0][c0 + 0] + s_acc[1][c0 + 0] - sv[0];
        float a1 = s_acc[0][c0 + 1] + s_acc[1][c0 + 1] - sv[1];
        float a2 = s_acc[0][c0 + 2] + s_acc[1][c0 + 2] - sv[2];
        float a3 = s_acc[0][c0 + 3] + s_acc[1][c0 + 3] - sv[3];
        if (cnt > 0) {
            float4 lw = *(const float4*)&lnw[c0];
            float4 lb = *(const float4*)&lnb[c0];
            o.x = (a0 * rc - mean2) * inv2 * lw.x + lb.x;
            o.y = (a1 * rc - mean2) * inv2 * lw.y + lb.y;
            o.z = (a2 * rc - mean2) * inv2 * lw.z + lb.z;
            o.w = (a3 * rc - mean2) * inv2 * lw.w + lb.w;
        } else {
            o.x = o.y = o.z = o.w = 0.f;   // ref: agg=0, cnt clamped -> 0
        }
        o.x = fmaxf(o.x + xr.x, 0.f);
        o.y = fmaxf(o.y + xr.y, 0.f);
        o.z = fmaxf(o.z + xr.z, 0.f);
        o.w = fmaxf(o.w + xr.w, 0.f);
        *(float4*)&Out[(size_t)n * DD + c0] = o;
    }
}

extern "C" void kernel_launch(void* const* d_in, const int* in_sizes, int n_in,
                              void* d_out, int out_size, void* d_ws, size_t ws_size,
                              hipStream_t stream) {
    const float* x    = (const float*)d_in[0];
    const int*   ei   = (const int*)d_in[1];
    const float* W1   = (const float*)d_in[2];
    const float* as1  = (const float*)d_in[3];
    const float* ad1  = (const float*)d_in[4];
    const float* b1   = (const float*)d_in[5];
    const float* ln1w = (const float*)d_in[6];
    const float* ln1b = (const float*)d_in[7];
    const float* W2   = (const float*)d_in[8];
    const float* as2  = (const float*)d_in[9];
    const float* ad2  = (const float*)d_in[10];
    const float* b2   = (const float*)d_in[11];
    const float* ln2w = (const float*)d_in[12];
    const float* ln2b = (const float*)d_in[13];
    float* out = (float*)d_out;

    char* p = (char*)d_ws;
    auto alloc = [&](size_t bytes) {
        void* r = (void*)p;
        p += (bytes + 255) & ~(size_t)255;
        return r;
    };
    int*    deg     = (int*)alloc((size_t)NN * 4);
    int*    row_ptr = (int*)alloc((size_t)(NN + 1) * 4);
    int*    cursor  = (int*)alloc((size_t)NN * 4);
    double* stats1  = (double*)alloc(16);
    double* stats2  = (double*)alloc(16);
    float2* pstats  = (float2*)alloc((size_t)NN * 8);
    int*    col     = (int*)alloc((size_t)EP * 4);
    bf16*   bufH    = (bf16*)alloc((size_t)NN * DD * 2);   // h1, later h2 (bf16, gathered)
    float*  bufF    = (float*)alloc((size_t)NN * DD * 4);  // out1 (fp32); later out2 (bf16 alias)
    bf16*   out2    = (bf16*)bufF;                         // alias: out1 dead before out2 written
    float*  aS1     = (float*)alloc((size_t)NN * 2 * 4);
    float*  aD1     = (float*)alloc((size_t)NN * 2 * 4);
    float*  aS2     = (float*)alloc((size_t)NN * 4);
    float*  aD2     = (float*)alloc((size_t)NN * 4);

    hipMemsetAsync(deg, 0, (size_t)NN * 4, stream);

    hist_kernel<<<(EP + 255) / 256, 256, 0, stream>>>(ei, deg);
    scan_kernel<<<1, 1024, 0, stream>>>(deg, row_ptr, cursor);
    scatter_kernel<<<(EP + 255) / 256, 256, 0, stream>>>(ei, cursor, col);

    // layer 1: GATConv(128 -> 64, heads=2, concat); LN1+relu deferred into next gemm
    gemm_attn<2, false><<<(NN + 7) / 8, 128, 0, stream>>>(x, W1, as1, ad1,
                                                          nullptr, nullptr, nullptr,
                                                          bufH, aS1, aD1);
    gat_agg<2, float><<<NN, 128, 0, stream>>>(row_ptr, col, bufH, aS1, aD1, b1, bufF, pstats);
    reduce_stats_kernel<<<1, 1024, 0, stream>>>(pstats, stats1);

    // layer 2: GATConv(128 -> 128, heads=1), input = relu(ln1(out1)) fused into gemm
    gemm_attn<1, true><<<(NN + 7) / 8, 128, 0, stream>>>(bufF, W2, as2, ad2,
                                                         stats1, ln1w, ln1b,
                                                         bufH, aS2, aD2);
    gat_agg<1, bf16><<<NN, 128, 0, stream>>>(row_ptr, col, bufH, aS2, aD2, b2, out2, pstats);
    reduce_stats_kernel<<<1, 1024, 0, stream>>>(pstats, stats2);

    // SimpleConv mean over original edges + LN2 affine + residual + relu (fused)
    simpleconv_kernel<<<NN, 128, 0, stream>>>(row_ptr, col, out2, x,
                                              stats2, ln2w, ln2b, out);
}